// Round 6
// baseline (275.812 us; speedup 1.0000x reference)
//
#include <hip/hip_runtime.h>

// ODENet forward, round 19: RK2 FAILED accuracy (0.1406 > 0.12375) -> revert
// to RK3 math (validated 0.046875) and remove phases ALGEBRAICALLY:
// W31 = W3@W1 fusion. z-space recurrence: z1(S_{j+1}) = z1(y) + c*(h2@W31
// + b31), so layer-3 + layer-1 collapse into one 256x256 MFMA and the
// 128-dim state is never materialized. Stage 3 runs L2 only (k3 feeds y'
// only). Epilogue fused too: pred = x@Wl + (M@W3l)/6 + (bl + b3@Wl) with
// M = h2_1 + 4*h2_2 + h2_3 in f32 regs; both projections via MFMA with
// 16-col-padded A-frags (Wlf/W3lf) -> shuffle-reduce + partials LDS gone.
// Barriers/tile 10 -> 8; no Y regs; S2/S3 no longer f16-quantized (z-space
// f32 accumulators) -> accuracy ~= r17. W31/W3l/b31/blsum precomputed by
// fuse_weights kernel (fp32 dot, single f16 quantization).
// Register audit: peak ~250/256 (WA2 64 + W31f 64 + Z1/ZA/M/D rotating 96
// + temps). Spill tell = FETCH/WRITE inflation; fallback = unfuse Wl.
// ws layout (bytes): A1 f16 @0 (64K), A2 @65536 (128K), W31f @196608
// (128K), Wlf @327680 (4K), W3lf @331776 (8K), b31 f32 @339968 (1K),
// blsum @340992 (40). Total ~341KB of d_ws.
// Core (validated r17): b128 B-frags, lgkm-only barriers, raw[2] async x
// prefetch, no-spill weight residency, f16 MFMA 16x16x32, ping-pong 2x32KB,
// grid 256 persistent, 4 row-tiles/WG.
// HISTORY (do not regress): r5 launch_bounds(512,4) -> weight spill; r8
// inline f32 gather -> spill; r11 LDS union overlays -> divergence; r13
// full-unroll float4 epilogue -> +23us; r18 RK2 -> absmax fail.

typedef _Float16 half8 __attribute__((ext_vector_type(8)));
typedef _Float16 half4 __attribute__((ext_vector_type(4)));
typedef float    floatx4 __attribute__((ext_vector_type(4)));

#define MFMA16 __builtin_amdgcn_mfma_f32_16x16x32_f16

constexpr int DDIM  = 118;
constexpr int TILES = 4;      // row-tiles of 64 per WG (grid 256)

// async global->LDS, 16B/lane, LDS dest = wave-uniform base + lane*16
#define GLOAD_LDS16(g, p) __builtin_amdgcn_global_load_lds(              \
    (const __attribute__((address_space(1))) void*)(g),                  \
    (__attribute__((address_space(3))) void*)(p), 16, 0, 0)

// LDS-producer/consumer barrier WITHOUT vmcnt drain.
#define BAR_LGKM() do {                                                  \
    asm volatile("s_waitcnt lgkmcnt(0)" ::: "memory");                   \
    __builtin_amdgcn_s_barrier();                                        \
    asm volatile("" ::: "memory");                                       \
  } while (0)

// B-fragment: frag(kc,nb) = 64 lanes x 8 f16; lane l holds
// (k = 32kc + 8(l>>4) + t, n = 16nb + (l&15)), t=0..7.
__device__ __forceinline__ int FRAGB(int kc, int nb) {
  return (kc*4 + nb) * 512;
}

struct SMemT {
  _Float16 b[2][16384];   // ping-pong activation buffers, 32KB each
  float raw[2][7552];     // x staging, double-buffered async prefetch
  float epi_x[16 * 66];   // x@Wl + blsum, rows o=0..15 (4224B)
  float cb1[256];         // b1
  float cb2[256];         // b2
  float cb31[256];        // b31 = b3@W1
  float cbls[10];         // blsum = bl + b3@Wl
};                        // total ~133.3KB < 160KB/CU

// ---- pack A1/A2: fp32 W[K][N] (k-major) -> A-frag f16 ----
__global__ void pack_weights_all(const float* __restrict__ W1,
                                 const float* __restrict__ W2,
                                 _Float16* __restrict__ out)
{
  int idx = blockIdx.x * 256 + threadIdx.x;     // 0 .. 98303
  const float* W; int kcBits, base;
  if (idx < 32768) { W = W1; kcBits = 2; base = 0;     }
  else             { W = W2; kcBits = 3; base = 32768; }
  int rel = idx - base;
  int j  = rel & 7;
  int L  = (rel >> 3) & 63;
  int blk = rel >> 9;
  int kc = blk & ((1 << kcBits) - 1);
  int mb = blk >> kcBits;
  int k = 32*kc + 8*(L >> 4) + j;
  int m = 16*mb + (L & 15);
  out[idx] = (_Float16)W[k*256 + m];
}

// ---- fuse: W31 = W3@W1 frags, W3lf/Wlf frags, b31, blsum ----
__global__ void fuse_weights(const float* __restrict__ W1,
                             const float* __restrict__ W3,
                             const float* __restrict__ Wl,
                             const float* __restrict__ b3,
                             const float* __restrict__ bl,
                             _Float16* __restrict__ fr,
                             float* __restrict__ b31o,
                             float* __restrict__ blso)
{
  __shared__ float w3row[128];
  const int tid = threadIdx.x;
  const int blk = blockIdx.x;
  if (blk < 256) {
    const int k = blk;                       // h2-dim row of W31
    if (tid < 128) w3row[tid] = W3[k*128 + tid];
    __syncthreads();
    // W31[k][m] = sum_j W3[k][j] * W1[j][m]
    float acc = 0.f;
    for (int j = 0; j < 128; ++j) acc = fmaf(w3row[j], W1[j*256 + tid], acc);
    {
      int m = tid;
      int mb = m >> 4, kc = k >> 5, j7 = k & 7;
      int L = ((k & 31) >> 3) * 16 + (m & 15);
      fr[98304 + ((mb*8 + kc)*64 + L)*8 + j7] = (_Float16)acc;
    }
    // W3lf[k][m<16] (zero-pad m>=10): W3l[k][o] = sum_j W3[k][j]*Wl[j][o]
    if (tid < 16) {
      float a2 = 0.f;
      if (tid < 10)
        for (int j = 0; j < 128; ++j) a2 = fmaf(w3row[j], Wl[j*10 + tid], a2);
      int kc = k >> 5, j7 = k & 7;
      int L = ((k & 31) >> 3) * 16 + tid;
      fr[165888 + (kc*64 + L)*8 + j7] = (_Float16)a2;
    }
  } else if (blk == 256) {
    // b31[m] = sum_j b3[j] * W1[j][m];  blsum[o] = bl[o] + sum_j b3[j]*Wl[j][o]
    float acc = 0.f;
    for (int j = 0; j < 128; ++j) acc = fmaf(b3[j], W1[j*256 + tid], acc);
    b31o[tid] = acc;
    if (tid < 10) {
      float a2 = bl[tid];
      for (int j = 0; j < 128; ++j) a2 = fmaf(b3[j], Wl[j*10 + tid], a2);
      blso[tid] = a2;
    }
  } else {
    // Wlf frags: 128 x 16 (zero-pad m>=10)
    for (int e = tid; e < 2048; e += 256) {
      int k = e >> 4, m = e & 15;
      float v = (m < 10) ? Wl[k*10 + m] : 0.f;
      int kc = k >> 5, j7 = k & 7;
      int L = ((k & 31) >> 3) * 16 + m;
      fr[163840 + (kc*64 + L)*8 + j7] = (_Float16)v;
    }
  }
}

__global__ __launch_bounds__(512, 2)
void ode_kernel(const float* __restrict__ x,
                const float* __restrict__ b1v, const float* __restrict__ b2v,
                const _Float16* __restrict__ Aw,
                const float* __restrict__ b31g, const float* __restrict__ blsg,
                float* __restrict__ out)
{
  __shared__ SMemT sm;
  const int tid = threadIdx.x;
  const int w   = tid >> 6;    // wave 0..7
  const int l   = tid & 63;
  const int q   = l >> 4;
  const int c   = l & 15;

  const int sh  = q & 1;       // store-side half (t = 4*sh + r)
  const int qh  = q >> 1;
  const int lb  = l * 8;       // lane's B-frag offset (f16 units)

  // ---- issue async prefetch of tile 0's x block ----
  {
    const float* src = x + (size_t)(blockIdx.x * (64 * TILES)) * DDIM;
    float* dst = sm.raw[0];
    for (int ch = w; ch < 30; ch += 8) {
      int idx = ch * 64 + l;
      if (idx < 1888) GLOAD_LDS16(src + (size_t)idx * 4, dst + ch * 256);
    }
  }

  // ---- stage constants into LDS (once per WG) ----
  if (tid < 256) {
    sm.cb1[tid]  = b1v[tid];
    sm.cb2[tid]  = b2v[tid];
    sm.cb31[tid] = b31g[tid];
  }
  if (tid < 10) sm.cbls[tid] = blsg[tid];

  // ---- persistent weight A-frags: WA2 + W31f = 128 VGPRs/wave ----
  const _Float16* A2  = Aw + 32768;
  const _Float16* A31 = Aw + 98304;
  half8 WA2[2][8], W31f[2][8];
#pragma unroll
  for (int i = 0; i < 2; ++i)
#pragma unroll
    for (int kc = 0; kc < 8; ++kc) {
      WA2[i][kc]  = *(const half8*)&A2 [((((2*w+i)*8 + kc)*64) + l)*8];
      W31f[i][kc] = *(const half8*)&A31[((((2*w+i)*8 + kc)*64) + l)*8];
    }

  const _Float16* A1  = Aw;            // 16mb x 4kc
  const _Float16* Awl = Aw + 163840;   // Wlf  (1mb x 4kc)
  const _Float16* A3l = Aw + 165888;   // W3lf (1mb x 8kc)

#pragma unroll 1
  for (int t = 0; t < TILES; ++t) {
    const int R = blockIdx.x * (64 * TILES) + t * 64;
    const float* rawc = sm.raw[t & 1];

    // drain this tile's prefetch; fence LDS reuse (b[0], epi_x, raw)
    asm volatile("s_waitcnt vmcnt(0)" ::: "memory");
    BAR_LGKM();

    // ---- per-tile A-frag loads (oldest vmem: don't wait on prefetch) ----
    half8 WA1t[2][4], WAlt[4];
#pragma unroll
    for (int i = 0; i < 2; ++i)
#pragma unroll
      for (int kc = 0; kc < 4; ++kc)
        WA1t[i][kc] = *(const half8*)&A1[((((2*w+i)*4 + kc)*64) + l)*8];
#pragma unroll
    for (int kc = 0; kc < 4; ++kc)
      WAlt[kc] = *(const half8*)&Awl[(kc*64 + l)*8];

    // ---- issue NEXT tile's prefetch ----
    if (t + 1 < TILES) {
      const float* src = x + (size_t)(R + 64) * DDIM;
      float* dst = sm.raw[(t + 1) & 1];
      for (int ch = w; ch < 30; ch += 8) {
        int idx = ch * 64 + l;
        if (idx < 1888) GLOAD_LDS16(src + (size_t)idx * 4, dst + ch * 256);
      }
    }

    // ---- build x_aug frags in b[0] (kc<4, zero-pad k>=118) ----
    for (int g = tid; g < 1024; g += 512) {
      int ll = g & 63;
      int nb = (g >> 6) & 3;
      int kc = g >> 8;
      int n  = 16*nb + (ll & 15);
      int k0 = 32*kc + 8*(ll >> 4);
      half8 v;
#pragma unroll
      for (int tt = 0; tt < 8; ++tt) {
        int k = k0 + tt;
        v[tt] = (_Float16)((k < DDIM) ? rawc[n*DDIM + k] : 0.0f);
      }
      *(half8*)&sm.b[0][FRAGB(kc, nb) + ll*8] = v;
    }
    BAR_LGKM();        // x frags ready

    floatx4 Z1[2][4];  // z1(y) = y@W1 + b1 (f32, persistent this tile)
    floatx4 ZA[2][4];  // Z3 partial = z1(y) - D1
    floatx4 M[2][4];   // h2_1 + 4 h2_2 + h2_3

    // ==== U phase: Z1 = x@W1 + b1;  epi_x = x@Wl + blsum (wave 0) ====
    {
      floatx4 CP[4];
      float bb[4];
#pragma unroll
      for (int r = 0; r < 4; ++r) bb[r] = sm.cbls[4*q + r];
#pragma unroll
      for (int i = 0; i < 2; ++i)
#pragma unroll
        for (int nb = 0; nb < 4; ++nb)
#pragma unroll
          for (int r = 0; r < 4; ++r)
            Z1[i][nb][r] = sm.cb1[32*w + 16*i + 4*q + r];
#pragma unroll
      for (int nb = 0; nb < 4; ++nb)
#pragma unroll
        for (int r = 0; r < 4; ++r) CP[nb][r] = bb[r];
#pragma unroll
      for (int kc = 0; kc < 4; ++kc) {
        half8 bf[4];
#pragma unroll
        for (int nb = 0; nb < 4; ++nb)
          bf[nb] = *(const half8*)&sm.b[0][FRAGB(kc, nb) + lb];
#pragma unroll
        for (int i = 0; i < 2; ++i)
#pragma unroll
          for (int nb = 0; nb < 4; ++nb)
            Z1[i][nb] = MFMA16(WA1t[i][kc], bf[nb], Z1[i][nb], 0, 0, 0);
#pragma unroll
        for (int nb = 0; nb < 4; ++nb)
          CP[nb] = MFMA16(WAlt[kc], bf[nb], CP[nb], 0, 0, 0);
      }
      // h1_1 = relu(Z1) -> b[1]
#pragma unroll
      for (int i = 0; i < 2; ++i)
#pragma unroll
        for (int nb = 0; nb < 4; ++nb) {
          half4 v;
#pragma unroll
          for (int r = 0; r < 4; ++r) v[r] = (_Float16)fmaxf(Z1[i][nb][r], 0.0f);
          *(half4*)&sm.b[1][FRAGB(w, nb) + (16*(2*i+qh) + c)*8 + sh*4] = v;
        }
      if (w == 0) {
#pragma unroll
        for (int nb = 0; nb < 4; ++nb)
#pragma unroll
          for (int r = 0; r < 4; ++r)
            sm.epi_x[(4*q + r)*66 + 16*nb + c] = CP[nb][r];
      }
    }
    BAR_LGKM();        // h1_1 + epi_x ready

    // ==== stage1-L2: C2 = h1_1@W2 + b2; h2_1 -> b[0]; M = h2_1 ====
    {
      floatx4 C2[2][4];
#pragma unroll
      for (int i = 0; i < 2; ++i)
#pragma unroll
        for (int nb = 0; nb < 4; ++nb)
#pragma unroll
          for (int r = 0; r < 4; ++r)
            C2[i][nb][r] = sm.cb2[32*w + 16*i + 4*q + r];
#pragma unroll
      for (int kc = 0; kc < 8; ++kc) {
        half8 bf[4];
#pragma unroll
        for (int nb = 0; nb < 4; ++nb)
          bf[nb] = *(const half8*)&sm.b[1][FRAGB(kc, nb) + lb];
#pragma unroll
        for (int i = 0; i < 2; ++i)
#pragma unroll
          for (int nb = 0; nb < 4; ++nb)
            C2[i][nb] = MFMA16(WA2[i][kc], bf[nb], C2[i][nb], 0, 0, 0);
      }
#pragma unroll
      for (int i = 0; i < 2; ++i)
#pragma unroll
        for (int nb = 0; nb < 4; ++nb) {
          half4 v;
#pragma unroll
          for (int r = 0; r < 4; ++r) {
            float hv = fmaxf(C2[i][nb][r], 0.0f);
            M[i][nb][r] = hv;
            v[r] = (_Float16)hv;
          }
          *(half4*)&sm.b[0][FRAGB(w, nb) + (16*(2*i+qh) + c)*8 + sh*4] = v;
        }
    }
    BAR_LGKM();        // h2_1 ready

    // ==== stage1-W31: D1 = h2_1@W31 + b31; Z2 = Z1 + D1/2; ZA = Z1 - D1 ====
    {
      floatx4 D[2][4];
#pragma unroll
      for (int i = 0; i < 2; ++i)
#pragma unroll
        for (int nb = 0; nb < 4; ++nb)
#pragma unroll
          for (int r = 0; r < 4; ++r)
            D[i][nb][r] = sm.cb31[32*w + 16*i + 4*q + r];
#pragma unroll
      for (int kc = 0; kc < 8; ++kc) {
        half8 bf[4];
#pragma unroll
        for (int nb = 0; nb < 4; ++nb)
          bf[nb] = *(const half8*)&sm.b[0][FRAGB(kc, nb) + lb];
#pragma unroll
        for (int i = 0; i < 2; ++i)
#pragma unroll
          for (int nb = 0; nb < 4; ++nb)
            D[i][nb] = MFMA16(W31f[i][kc], bf[nb], D[i][nb], 0, 0, 0);
      }
      // h1_2 = relu(Z1 + 0.5 D) -> b[1];  ZA = Z1 - D
#pragma unroll
      for (int i = 0; i < 2; ++i)
#pragma unroll
        for (int nb = 0; nb < 4; ++nb) {
          half4 v;
#pragma unroll
          for (int r = 0; r < 4; ++r) {
            float z  = Z1[i][nb][r];
            float d  = D[i][nb][r];
            ZA[i][nb][r] = z - d;
            v[r] = (_Float16)fmaxf(z + 0.5f*d, 0.0f);
          }
          *(half4*)&sm.b[1][FRAGB(w, nb) + (16*(2*i+qh) + c)*8 + sh*4] = v;
        }
    }
    BAR_LGKM();        // h1_2 ready

    // ==== stage2-L2: h2_2 -> b[0]; M += 4 h2_2 ====
    {
      floatx4 C2[2][4];
#pragma unroll
      for (int i = 0; i < 2; ++i)
#pragma unroll
        for (int nb = 0; nb < 4; ++nb)
#pragma unroll
          for (int r = 0; r < 4; ++r)
            C2[i][nb][r] = sm.cb2[32*w + 16*i + 4*q + r];
#pragma unroll
      for (int kc = 0; kc < 8; ++kc) {
        half8 bf[4];
#pragma unroll
        for (int nb = 0; nb < 4; ++nb)
          bf[nb] = *(const half8*)&sm.b[1][FRAGB(kc, nb) + lb];
#pragma unroll
        for (int i = 0; i < 2; ++i)
#pragma unroll
          for (int nb = 0; nb < 4; ++nb)
            C2[i][nb] = MFMA16(WA2[i][kc], bf[nb], C2[i][nb], 0, 0, 0);
      }
#pragma unroll
      for (int i = 0; i < 2; ++i)
#pragma unroll
        for (int nb = 0; nb < 4; ++nb) {
          half4 v;
#pragma unroll
          for (int r = 0; r < 4; ++r) {
            float hv = fmaxf(C2[i][nb][r], 0.0f);
            M[i][nb][r] = fmaf(4.0f, hv, M[i][nb][r]);
            v[r] = (_Float16)hv;
          }
          *(half4*)&sm.b[0][FRAGB(w, nb) + (16*(2*i+qh) + c)*8 + sh*4] = v;
        }
    }
    BAR_LGKM();        // h2_2 ready

    // ==== stage2-W31: D2 = h2_2@W31 + b31; h1_3 = relu(ZA + 2 D2) ====
    {
      floatx4 D[2][4];
#pragma unroll
      for (int i = 0; i < 2; ++i)
#pragma unroll
        for (int nb = 0; nb < 4; ++nb)
#pragma unroll
          for (int r = 0; r < 4; ++r)
            D[i][nb][r] = sm.cb31[32*w + 16*i + 4*q + r];
#pragma unroll
      for (int kc = 0; kc < 8; ++kc) {
        half8 bf[4];
#pragma unroll
        for (int nb = 0; nb < 4; ++nb)
          bf[nb] = *(const half8*)&sm.b[0][FRAGB(kc, nb) + lb];
#pragma unroll
        for (int i = 0; i < 2; ++i)
#pragma unroll
          for (int nb = 0; nb < 4; ++nb)
            D[i][nb] = MFMA16(W31f[i][kc], bf[nb], D[i][nb], 0, 0, 0);
      }
#pragma unroll
      for (int i = 0; i < 2; ++i)
#pragma unroll
        for (int nb = 0; nb < 4; ++nb) {
          half4 v;
#pragma unroll
          for (int r = 0; r < 4; ++r)
            v[r] = (_Float16)fmaxf(ZA[i][nb][r] + 2.0f*D[i][nb][r], 0.0f);
          *(half4*)&sm.b[1][FRAGB(w, nb) + (16*(2*i+qh) + c)*8 + sh*4] = v;
        }
    }
    BAR_LGKM();        // h1_3 ready

    // ==== stage3-L2: M += relu(.); store M/6 frags -> b[0] ====
    half8 W3t[8];      // W3lf A-frags (global, in flight during MFMAs)
#pragma unroll
    for (int kc = 0; kc < 8; ++kc)
      W3t[kc] = *(const half8*)&A3l[(kc*64 + l)*8];
    {
      floatx4 C2[2][4];
#pragma unroll
      for (int i = 0; i < 2; ++i)
#pragma unroll
        for (int nb = 0; nb < 4; ++nb)
#pragma unroll
          for (int r = 0; r < 4; ++r)
            C2[i][nb][r] = sm.cb2[32*w + 16*i + 4*q + r];
#pragma unroll
      for (int kc = 0; kc < 8; ++kc) {
        half8 bf[4];
#pragma unroll
        for (int nb = 0; nb < 4; ++nb)
          bf[nb] = *(const half8*)&sm.b[1][FRAGB(kc, nb) + lb];
#pragma unroll
        for (int i = 0; i < 2; ++i)
#pragma unroll
          for (int nb = 0; nb < 4; ++nb)
            C2[i][nb] = MFMA16(WA2[i][kc], bf[nb], C2[i][nb], 0, 0, 0);
      }
#pragma unroll
      for (int i = 0; i < 2; ++i)
#pragma unroll
        for (int nb = 0; nb < 4; ++nb) {
          half4 v;
#pragma unroll
          for (int r = 0; r < 4; ++r) {
            float mval = M[i][nb][r] + fmaxf(C2[i][nb][r], 0.0f);
            v[r] = (_Float16)(mval * (1.0f/6.0f));
          }
          *(half4*)&sm.b[0][FRAGB(w, nb) + (16*(2*i+qh) + c)*8 + sh*4] = v;
        }
    }
    BAR_LGKM();        // M/6 frags ready

    // ==== M-proj: pred = epi_x + (M/6)@W3l; store (wave 0) ====
    {
      floatx4 CF[4];
#pragma unroll
      for (int nb = 0; nb < 4; ++nb)
#pragma unroll
        for (int r = 0; r < 4; ++r)
          CF[nb][r] = sm.epi_x[(4*q + r)*66 + 16*nb + c];
#pragma unroll
      for (int kc = 0; kc < 8; ++kc) {
        half8 bf[4];
#pragma unroll
        for (int nb = 0; nb < 4; ++nb)
          bf[nb] = *(const half8*)&sm.b[0][FRAGB(kc, nb) + lb];
#pragma unroll
        for (int nb = 0; nb < 4; ++nb)
          CF[nb] = MFMA16(W3t[kc], bf[nb], CF[nb], 0, 0, 0);
      }
      if (w == 0) {
#pragma unroll
        for (int nb = 0; nb < 4; ++nb)
#pragma unroll
          for (int r = 0; r < 4; ++r) {
            int o = 4*q + r;
            if (o < 10)
              out[(size_t)(R + 16*nb + c)*10 + o] = CF[nb][r];
          }
      }
    }
    // no trailing barrier: next tile-top vmcnt(0)+BAR_LGKM fences reuse
  }
}

extern "C" void kernel_launch(void* const* d_in, const int* in_sizes, int n_in,
                              void* d_out, int out_size, void* d_ws, size_t ws_size,
                              hipStream_t stream) {
  const float* x  = (const float*)d_in[0];
  const float* W1 = (const float*)d_in[1];
  const float* b1 = (const float*)d_in[2];
  const float* W2 = (const float*)d_in[3];
  const float* b2 = (const float*)d_in[4];
  const float* W3 = (const float*)d_in[5];
  const float* b3 = (const float*)d_in[6];
  const float* Wl = (const float*)d_in[7];
  const float* bl = (const float*)d_in[8];
  float* out = (float*)d_out;

  _Float16* Aw  = (_Float16*)d_ws;                       // f16 frags (~332KB)
  float*    wsf = (float*)((char*)d_ws + 339968);        // b31[256], blsum[10]

  pack_weights_all<<<384, 256, 0, stream>>>(W1, W2, Aw);
  fuse_weights<<<258, 256, 0, stream>>>(W1, W3, Wl, b3, bl, Aw, wsf, wsf + 256);
  ode_kernel<<<256, 512, 0, stream>>>(x, b1, b2, Aw, wsf, wsf + 256, out);
}